// Round 8
// baseline (577.582 us; speedup 1.0000x reference)
//
#include <hip/hip_runtime.h>
#include <hip/hip_bf16.h>
#include <stdint.h>

typedef __attribute__((ext_vector_type(4))) float f32x4;
typedef __attribute__((ext_vector_type(8))) short s16x8;

__device__ __forceinline__ short f2bf(float f) {
  union { float f; uint32_t u; } v; v.f = f;
  uint32_t r = v.u + 0x7FFFu + ((v.u >> 16) & 1u);
  return (short)(r >> 16);
}

__device__ __forceinline__ void async16(const void* g, void* l) {
  __builtin_amdgcn_global_load_lds(
      (const __attribute__((address_space(1))) void*)g,
      (__attribute__((address_space(3))) void*)l, 16, 0, 0);
}

// ---------------- cast x (fp32 -> bf16), 8 elems/thread ----------------
__global__ __launch_bounds__(256) void k_cast_bf16(const float* __restrict__ in,
                                                   short* __restrict__ out, int n8) {
  int i = blockIdx.x * 256 + threadIdx.x;
  if (i >= n8) return;
  const float4* p = (const float4*)in + (size_t)i * 2;
  float4 a = p[0], b = p[1];
  s16x8 o;
  o[0] = f2bf(a.x); o[1] = f2bf(a.y); o[2] = f2bf(a.z); o[3] = f2bf(a.w);
  o[4] = f2bf(b.x); o[5] = f2bf(b.y); o[6] = f2bf(b.z); o[7] = f2bf(b.w);
  ((s16x8*)out)[i] = o;
}

// -------- LDS-tiled transpose+cast: out[n][k] = bf16(in[k][n]) --------
__global__ __launch_bounds__(256) void k_transpose_cast(const float* __restrict__ in,
                                                        short* __restrict__ out,
                                                        int K, int N) {
  __shared__ float tile[64][65];
  const int bx = blockIdx.x;
  const int by = blockIdx.y;
  const int tx = threadIdx.x & 63, ty = threadIdx.x >> 6;
#pragma unroll
  for (int r = ty; r < 64; r += 4)
    tile[r][tx] = in[(size_t)(by * 64 + r) * N + bx * 64 + tx];
  __syncthreads();
#pragma unroll
  for (int r = ty; r < 64; r += 4)
    out[(size_t)(bx * 64 + r) * K + by * 64 + tx] = f2bf(tile[tx][r]);
}

// ===== persistent 256x256 GEMM, reg-double-buffered k-split pipeline =====
// LDS: 4 regions idx=(buf<<1)|ks, each 32KB: A[256r][32k] @+0, B[256r][32k] @+8192.
// Slot s = 2T+half. Even slot: MFMA on (T,ks0) regs, read (T,ks1), stage (T+2,ks0).
// Odd: MFMA (T,ks1), read (T+1,ks0), stage (T+2,ks1). vmcnt(8)=3-slot stage depth.
// One barrier/slot; ds_reads overlap the MFMA cluster (different pipes).
// Chunk swizzle g' = g ^ ((row>>1)&3): 8 chunks/bank-class floor, 0 conflicts.
#define RGN 16384  // shorts per region

template <bool F32OUT, int NBN>
__global__ __launch_bounds__(512, 1) void k_gemmks(const short* __restrict__ A,
                                                   const short* __restrict__ Bw,
                                                   const float* __restrict__ bias,
                                                   void* __restrict__ C,
                                                   int N, int K, int nrounds) {
  __shared__ short lds[4 * RGN];  // 128 KiB
  const int t = threadIdx.x;
  const int w = t >> 6, l = t & 63;
  const int wm = w >> 2, wn = w & 3;
  const int swz = (((int)blockIdx.x & 7) << 5) + ((int)blockIdx.x >> 3);

  // per-lane ds_read offset (shorts): row (l&15), chunk (l>>4)^( (row>>1)&3 )
  const int laneOff = (l & 15) * 32 + (((l >> 4) ^ ((l >> 1) & 3)) << 3);

  auto stageR = [&](int bmv, int bnv, int kt, int ks) {
    short* base = lds + (((kt & 1) << 1) + ks) * RGN;
#pragma unroll
    for (int L = 0; L < 2; ++L) {
      int pc = L * 512 + t;
      int pr = pc >> 2;
      int gg = (pc & 3) ^ ((pr >> 1) & 3);
      async16(A + (size_t)(bmv * 256 + pr) * K + kt * 64 + ks * 32 + gg * 8,
              base + (L * 512 + (t & ~63)) * 8);
    }
#pragma unroll
    for (int L = 0; L < 2; ++L) {
      int pc = L * 512 + t;
      int pr = pc >> 2;
      int gg = (pc & 3) ^ ((pr >> 1) & 3);
      async16(Bw + (size_t)(bnv * 256 + pr) * K + kt * 64 + ks * 32 + gg * 8,
              base + 8192 + (L * 512 + (t & ~63)) * 8);
    }
  };

#define RD_FRAGS(NA, NB, RIDX)                                                        \
  _Pragma("unroll") for (int ai = 0; ai < 8; ++ai)                                    \
      NA[ai] = *(const s16x8*)(lds + (RIDX) * RGN + (wm * 128 + ai * 16) * 32 + laneOff); \
  _Pragma("unroll") for (int nj = 0; nj < 4; ++nj)                                    \
      NB[nj] = *(const s16x8*)(lds + (RIDX) * RGN + 8192 + (wn * 64 + nj * 16) * 32 + laneOff);

#define MFMAS(CA, CB)                                                                 \
  __builtin_amdgcn_s_setprio(1);                                                      \
  _Pragma("unroll") for (int nj = 0; nj < 4; ++nj)                                    \
      _Pragma("unroll") for (int ai = 0; ai < 8; ++ai)                                \
          acc[ai][nj] = __builtin_amdgcn_mfma_f32_16x16x32_bf16(CA[ai], CB[nj], acc[ai][nj], 0, 0, 0); \
  __builtin_amdgcn_s_setprio(0);

  f32x4 acc[8][4] = {};
  s16x8 Xa[8], Xb[4], Ya[8], Yb[4];

  // prologue: stage K-tiles 0,1 of first tile; land tile0; read (0,ks0)
  {
    const int tau0 = swz;
    const int bm0 = tau0 / NBN, bn0 = tau0 % NBN;
    stageR(bm0, bn0, 0, 0);
    stageR(bm0, bn0, 0, 1);
    stageR(bm0, bn0, 1, 0);
    stageR(bm0, bn0, 1, 1);
  }
  asm volatile("s_waitcnt vmcnt(8)" ::: "memory");
  __builtin_amdgcn_s_barrier();
  RD_FRAGS(Xa, Xb, 0);
  asm volatile("s_waitcnt lgkmcnt(0)" ::: "memory");

  for (int j = 0; j < nrounds; ++j) {
    const int tau = swz + (j << 8);
    const int bmc = tau / NBN, bnc = tau % NBN;
    const int tau1 = tau + 256;
    const int bm1 = tau1 / NBN, bn1 = tau1 % NBN;
    const bool more = (j + 1) < nrounds;

#pragma unroll
    for (int k = 0; k < 8; ++k) {
      const int skt = (k + 2) & 7;
      const int sbm = (k < 6) ? bmc : bm1;
      const int sbn = (k < 6) ? bnc : bn1;
      const bool sg = (k < 6) ? true : more;
      // ---- even slot: MFMA (T,ks0)=X ; read (T,ks1)->Y ; stage (T+2,ks0)
      asm volatile("s_waitcnt vmcnt(8)" ::: "memory");
      __builtin_amdgcn_s_barrier();
      RD_FRAGS(Ya, Yb, ((k & 1) << 1) + 1);
      if (sg) stageR(sbm, sbn, skt, 0);
      __builtin_amdgcn_sched_barrier(0);
      MFMAS(Xa, Xb);
      asm volatile("s_waitcnt lgkmcnt(0)" ::: "memory");
      __builtin_amdgcn_sched_barrier(0);
      // ---- odd slot: MFMA (T,ks1)=Y ; read (T+1,ks0)->X ; stage (T+2,ks1)
      asm volatile("s_waitcnt vmcnt(8)" ::: "memory");
      __builtin_amdgcn_s_barrier();
      if (k < 7 || more) { RD_FRAGS(Xa, Xb, (((k + 1) & 1) << 1)); }
      if (sg) stageR(sbm, sbn, skt, 1);
      __builtin_amdgcn_sched_barrier(0);
      MFMAS(Ya, Yb);
      asm volatile("s_waitcnt lgkmcnt(0)" ::: "memory");
      __builtin_amdgcn_sched_barrier(0);
    }

    // epilogue tile j (overlaps next tile's pipeline; stores drain at next vmcnt)
#pragma unroll
    for (int ai = 0; ai < 8; ++ai)
#pragma unroll
      for (int nj = 0; nj < 4; ++nj) {
        int col = bnc * 256 + wn * 64 + nj * 16 + (l & 15);
        float bv = bias[col];
#pragma unroll
        for (int r = 0; r < 4; ++r) {
          int row = bmc * 256 + wm * 128 + ai * 16 + (l >> 4) * 4 + r;
          float vv = acc[ai][nj][r] + bv;
          if (F32OUT)
            ((float*)C)[(size_t)row * N + col] = vv;
          else
            ((short*)C)[(size_t)row * N + col] = f2bf(vv);
        }
      }
#pragma unroll
    for (int ai = 0; ai < 8; ++ai)
#pragma unroll
      for (int nj = 0; nj < 4; ++nj)
        acc[ai][nj] = (f32x4){0.f, 0.f, 0.f, 0.f};
  }
#undef RD_FRAGS
#undef MFMAS
}

// ---------------- fused window attention: 1 wave per (b,h) ----------------
__global__ __launch_bounds__(256) void k_attn(const short* __restrict__ qkv,
                                              const float* __restrict__ mask,
                                              const float* __restrict__ bias_table,
                                              short* __restrict__ Y) {
  __shared__ float mask_lds[64 * 64];
  __shared__ float bias_lds[4][128];
  __shared__ short p_lds[4][64][72];

  const int t = threadIdx.x, wv = t >> 6, ln = t & 63;
  const int b = blockIdx.x;
  const int h = blockIdx.y * 4 + wv;

  const float4* mk = (const float4*)(mask + (size_t)(b & 63) * 4096);
#pragma unroll
  for (int u = 0; u < 4; ++u)
    ((float4*)mask_lds)[t + 256 * u] = mk[t + 256 * u];
  for (int u = ln; u < 127; u += 64) bias_lds[wv][u] = bias_table[u * 16 + h];
  __syncthreads();

  const short* qb = qkv + (size_t)b * 64 * 1536 + h * 32;

  s16x8 qf[4], kf[4];
#pragma unroll
  for (int i = 0; i < 4; ++i) {
    qf[i] = *(const s16x8*)(qb + (size_t)(16 * i + (ln & 15)) * 1536 + (ln >> 4) * 8);
    kf[i] = *(const s16x8*)(qb + (size_t)(16 * i + (ln & 15)) * 1536 + 512 + (ln >> 4) * 8);
  }
  f32x4 s[4][4] = {};
#pragma unroll
  for (int i = 0; i < 4; ++i)
#pragma unroll
    for (int j = 0; j < 4; ++j)
      s[i][j] = __builtin_amdgcn_mfma_f32_16x16x32_bf16(qf[i], kf[j], s[i][j], 0, 0, 0);

  const float scale = 0.17677669529663687f;
#pragma unroll
  for (int i = 0; i < 4; ++i)
#pragma unroll
    for (int r = 0; r < 4; ++r) {
      int nn = 16 * i + (ln >> 4) * 4 + r;
      float vals[4];
      float vmax = -1e30f;
#pragma unroll
      for (int j = 0; j < 4; ++j) {
        int mm = 16 * j + (ln & 15);
        float x = s[i][j][r] * scale + bias_lds[wv][nn - mm + 63] + mask_lds[nn * 64 + mm];
        vals[j] = x;
        vmax = fmaxf(vmax, x);
      }
#pragma unroll
      for (int d = 1; d < 16; d <<= 1) vmax = fmaxf(vmax, __shfl_xor(vmax, d, 64));
      float sum = 0.f;
#pragma unroll
      for (int j = 0; j < 4; ++j) {
        float p = __expf(vals[j] - vmax);
        vals[j] = p;
        sum += p;
      }
#pragma unroll
      for (int d = 1; d < 16; d <<= 1) sum += __shfl_xor(sum, d, 64);
      float rsv = 1.0f / sum;
#pragma unroll
      for (int j = 0; j < 4; ++j)
        p_lds[wv][nn][16 * j + (ln & 15)] = f2bf(vals[j] * rsv);
    }

  const short* vg = qb + 1024;
  f32x4 o[4][2] = {};
#pragma unroll
  for (int kk = 0; kk < 2; ++kk) {
    s16x8 pa[4];
#pragma unroll
    for (int i2 = 0; i2 < 4; ++i2)
      pa[i2] = *(const s16x8*)&p_lds[wv][16 * i2 + (ln & 15)][kk * 32 + (ln >> 4) * 8];
#pragma unroll
    for (int j2 = 0; j2 < 2; ++j2) {
      s16x8 vf;
#pragma unroll
      for (int jj = 0; jj < 8; ++jj)
        vf[jj] = vg[(size_t)(kk * 32 + (ln >> 4) * 8 + jj) * 1536 + 16 * j2 + (ln & 15)];
#pragma unroll
      for (int i2 = 0; i2 < 4; ++i2)
        o[i2][j2] = __builtin_amdgcn_mfma_f32_16x16x32_bf16(pa[i2], vf, o[i2][j2], 0, 0, 0);
    }
  }

#pragma unroll
  for (int i2 = 0; i2 < 4; ++i2)
#pragma unroll
    for (int j2 = 0; j2 < 2; ++j2)
#pragma unroll
      for (int r = 0; r < 4; ++r) {
        int n = 16 * i2 + (ln >> 4) * 4 + r;
        int d = 16 * j2 + (ln & 15);
        int rr = h * 64 + (b >> 4);
        int ss = (b & 15) * 4 + (n >> 4);
        int cc = (n & 15) * 32 + d;
        Y[((size_t)rr * 64 + ss) * 512 + cc] = f2bf(o[i2][j2][r]);
      }
}

extern "C" void kernel_launch(void* const* d_in, const int* in_sizes, int n_in,
                              void* d_out, int out_size, void* d_ws, size_t ws_size,
                              hipStream_t stream) {
  const float* x      = (const float*)d_in[0];
  const float* mask   = (const float*)d_in[1];
  const float* qkv_w  = (const float*)d_in[2];
  const float* qkv_b  = (const float*)d_in[3];
  const float* proj_w = (const float*)d_in[4];
  const float* proj_b = (const float*)d_in[5];
  const float* btab   = (const float*)d_in[6];
  float* out = (float*)d_out;

  char* w = (char*)d_ws;
  short* qkv_ws = (short*)w;                                             // 192 MiB
  short* xbf    = (short*)(w + (size_t)65536 * 1536 * 2);                // 64 MiB
  short* Y      = xbf;                                                   // reuse after GEMM1
  short* wT     = (short*)(w + (size_t)65536 * 1536 * 2 + (size_t)65536 * 512 * 2);
  short* projT  = wT + 1536 * 512;

  k_cast_bf16<<<16384, 256, 0, stream>>>(x, xbf, 33554432 / 8);
  k_transpose_cast<<<dim3(24, 8), 256, 0, stream>>>(qkv_w, wT, 512, 1536);
  k_transpose_cast<<<dim3(8, 8), 256, 0, stream>>>(proj_w, projT, 512, 512);
  k_gemmks<false, 6><<<256, 512, 0, stream>>>(xbf, wT, qkv_b, qkv_ws, 1536, 512, 6);
  k_attn<<<dim3(1024, 4), 256, 0, stream>>>(qkv_ws, mask, btab, Y);
  k_gemmks<true, 2><<<256, 512, 0, stream>>>(Y, projT, proj_b, out, 512, 512, 2);
}

// Round 9
// 290.527 us; speedup vs baseline: 1.9880x; 1.9880x over previous
//
#include <hip/hip_runtime.h>
#include <hip/hip_bf16.h>
#include <stdint.h>

typedef __attribute__((ext_vector_type(4))) float f32x4;
typedef __attribute__((ext_vector_type(8))) short s16x8;

__device__ __forceinline__ short f2bf(float f) {
  union { float f; uint32_t u; } v; v.f = f;
  uint32_t r = v.u + 0x7FFFu + ((v.u >> 16) & 1u);
  return (short)(r >> 16);
}
__device__ __forceinline__ uint32_t pack2bf(float a, float b) {
  return (uint32_t)(uint16_t)f2bf(a) | ((uint32_t)(uint16_t)f2bf(b) << 16);
}

__device__ __forceinline__ void async16(const void* g, void* l) {
  __builtin_amdgcn_global_load_lds(
      (const __attribute__((address_space(1))) void*)g,
      (__attribute__((address_space(3))) void*)l, 16, 0, 0);
}

// ---------------- cast x (fp32 -> bf16), 8 elems/thread ----------------
__global__ __launch_bounds__(256) void k_cast_bf16(const float* __restrict__ in,
                                                   short* __restrict__ out, int n8) {
  int i = blockIdx.x * 256 + threadIdx.x;
  if (i >= n8) return;
  const float4* p = (const float4*)in + (size_t)i * 2;
  float4 a = p[0], b = p[1];
  s16x8 o;
  o[0] = f2bf(a.x); o[1] = f2bf(a.y); o[2] = f2bf(a.z); o[3] = f2bf(a.w);
  o[4] = f2bf(b.x); o[5] = f2bf(b.y); o[6] = f2bf(b.z); o[7] = f2bf(b.w);
  ((s16x8*)out)[i] = o;
}

// -------- LDS-tiled transpose+cast: out[n][k] = bf16(in[k][n]) --------
__global__ __launch_bounds__(256) void k_transpose_cast(const float* __restrict__ in,
                                                        short* __restrict__ out,
                                                        int K, int N) {
  __shared__ float tile[64][65];
  const int bx = blockIdx.x;
  const int by = blockIdx.y;
  const int tx = threadIdx.x & 63, ty = threadIdx.x >> 6;
#pragma unroll
  for (int r = ty; r < 64; r += 4)
    tile[r][tx] = in[(size_t)(by * 64 + r) * N + bx * 64 + tx];
  __syncthreads();
#pragma unroll
  for (int r = ty; r < 64; r += 4)
    out[(size_t)(bx * 64 + r) * K + by * 64 + tx] = f2bf(tile[tx][r]);
}

// ===== persistent 256x256 8-phase bf16 GEMM — round-7 proven version, K templated =====
#define TILE_SH 16384  // 256*64 shorts per tile

template <bool F32OUT, int NBN, int KK>
__global__ __launch_bounds__(512, 2) void k_gemm256p(const short* __restrict__ A,
                                                     const short* __restrict__ Bw,
                                                     const float* __restrict__ bias,
                                                     void* __restrict__ C,
                                                     int N, int nrounds) {
  __shared__ short lds[2 * 2 * TILE_SH];  // 128 KiB
  const int t = threadIdx.x;
  const int w = t >> 6, l = t & 63;
  const int wm = w >> 2, wn = w & 3;
  const int swz = (((int)blockIdx.x & 7) << 5) + ((int)blockIdx.x >> 3);

  const int NT = KK >> 6;  // 8
  const int NS = nrounds * NT;

  auto stage = [&](const short* __restrict__ G, int row0, int kt, short* dst) {
#pragma unroll
    for (int L = 0; L < 2; ++L) {
      int cw = L * 512 + (t & ~63);
      int c = cw + l;
      int r = c >> 3, s = c & 7;
      async16(G + (size_t)(row0 + r) * KK + kt + ((s ^ (r & 7)) << 3), dst + cw * 8);
    }
  };
  auto issueA = [&](int step, int bmv, int hf) {
    int kt = step & 7;
    stage(A, bmv * 256 + hf * 128, kt * 64, lds + (kt & 1) * 32768 + hf * 8192);
  };
  auto issueB = [&](int step, int bnv, int hf) {
    int kt = step & 7;
    stage(Bw, bnv * 256 + hf * 128, kt * 64, lds + (kt & 1) * 32768 + TILE_SH + hf * 8192);
  };

  const int g = l >> 4, v = l & 7;
  int ofsA[2], ofsB[2];
#pragma unroll
  for (int ks = 0; ks < 2; ++ks) {
    ofsA[ks] = (wm * 128 + (l & 15)) * 64 + (((ks * 4 + g) ^ v) << 3);
    ofsB[ks] = (wn * 64 + (l & 15)) * 64 + (((ks * 4 + g) ^ v) << 3);
  }

  f32x4 acc[8][4] = {};
  s16x8 bfr[4][2];

  {
    const int bm0 = swz / NBN, bn0 = swz % NBN;
    issueB(0, bn0, 0); issueB(0, bn0, 1);
    issueA(0, bm0, 0); issueA(0, bm0, 1);
    issueB(1, bn0, 0); issueB(1, bn0, 1);
  }
  asm volatile("s_waitcnt vmcnt(4)" ::: "memory");
  __builtin_amdgcn_s_barrier();

#define PHASE(AI0, STAGE_STMT, TAIL_STMT)                                                                      \
  {                                                                                                            \
    s16x8 a00 = *(const s16x8*)(Ab + ofsA[0] + (AI0) * 1024);                                                  \
    s16x8 a01 = *(const s16x8*)(Ab + ofsA[1] + (AI0) * 1024);                                                  \
    s16x8 a10 = *(const s16x8*)(Ab + ofsA[0] + ((AI0) + 1) * 1024);                                            \
    s16x8 a11 = *(const s16x8*)(Ab + ofsA[1] + ((AI0) + 1) * 1024);                                            \
    STAGE_STMT;                                                                                                \
    __builtin_amdgcn_s_barrier();                                                                              \
    asm volatile("s_waitcnt lgkmcnt(0)" ::: "memory");                                                         \
    __builtin_amdgcn_s_setprio(1);                                                                             \
    _Pragma("unroll")                                                                                          \
    for (int nj = 0; nj < 4; ++nj) {                                                                           \
      acc[(AI0)][nj] = __builtin_amdgcn_mfma_f32_16x16x32_bf16(a00, bfr[nj][0], acc[(AI0)][nj], 0, 0, 0);      \
      acc[(AI0)][nj] = __builtin_amdgcn_mfma_f32_16x16x32_bf16(a01, bfr[nj][1], acc[(AI0)][nj], 0, 0, 0);      \
      acc[(AI0) + 1][nj] = __builtin_amdgcn_mfma_f32_16x16x32_bf16(a10, bfr[nj][0], acc[(AI0) + 1][nj], 0, 0, 0); \
      acc[(AI0) + 1][nj] = __builtin_amdgcn_mfma_f32_16x16x32_bf16(a11, bfr[nj][1], acc[(AI0) + 1][nj], 0, 0, 0); \
    }                                                                                                          \
    __builtin_amdgcn_s_setprio(0);                                                                             \
    TAIL_STMT;                                                                                                 \
    __builtin_amdgcn_s_barrier();                                                                              \
  }

  for (int j = 0; j < nrounds; ++j) {
    const int tauc = swz + (j << 8);
    const int bmc = tauc / NBN, bnc = tauc % NBN;
    for (int T = 0; T < NT; ++T) {
      const int s = (j << 3) + T;
      const int s1 = s + 1, s2 = s + 2;
      const int tau1 = swz + (((s1) >> 3) << 8);
      const int tau2 = swz + (((s2) >> 3) << 8);
      const int bm1 = tau1 / NBN;
      const int bn2 = tau2 % NBN;
      const short* Ab = lds + (T & 1) * 32768;
      const short* Bb = Ab + TILE_SH;
#pragma unroll
      for (int nj = 0; nj < 4; ++nj)
#pragma unroll
        for (int ks = 0; ks < 2; ++ks)
          bfr[nj][ks] = *(const s16x8*)(Bb + ofsB[ks] + nj * 1024);

      PHASE(0, if (s1 < NS) issueA(s1, bm1, 0), );
      PHASE(2, if (s1 < NS) issueA(s1, bm1, 1), );
      PHASE(4, if (s2 < NS) issueB(s2, bn2, 0), );
      PHASE(6, if (s2 < NS) issueB(s2, bn2, 1),
            if (s2 < NS) { asm volatile("s_waitcnt vmcnt(4)" ::: "memory"); }
            else if (s1 < NS) { asm volatile("s_waitcnt vmcnt(0)" ::: "memory"); });
    }

#pragma unroll
    for (int ai = 0; ai < 8; ++ai)
#pragma unroll
      for (int nj = 0; nj < 4; ++nj) {
        int col = bnc * 256 + wn * 64 + nj * 16 + (l & 15);
        float bv = bias[col];
#pragma unroll
        for (int r = 0; r < 4; ++r) {
          int row = bmc * 256 + wm * 128 + ai * 16 + (l >> 4) * 4 + r;
          float vv = acc[ai][nj][r] + bv;
          if (F32OUT)
            ((float*)C)[(size_t)row * N + col] = vv;
          else
            ((short*)C)[(size_t)row * N + col] = f2bf(vv);
        }
      }
#pragma unroll
    for (int ai = 0; ai < 8; ++ai)
#pragma unroll
      for (int nj = 0; nj < 4; ++nj)
        acc[ai][nj] = (f32x4){0.f, 0.f, 0.f, 0.f};
  }
#undef PHASE
}

// ============== fused window attention v2: swapped QK^T, 1 wave/(b,h) ==============
// s2[j][i] = mfma(K,Q): lane holds S[n][m], n=16i+(l&15), m=16j+4*(l>>4)+r
//  -> softmax row-reduce = local 16 + shfl_xor(16,32)   (16 shfl vs 128)
//  -> P written as packed b32 pairs (32 writes vs 64 scalar)
// PV as O^T = mfma(V^T, P^T): lane holds O[n][d], d=16j2+4*(l>>4)+r consecutive
//  -> Y stored as 8 packed uint2 (vs 32 scalar)
// V staged to LDS via 4 b128 global loads/lane; mask LDS XOR-swizzled (both sides).
__global__ __launch_bounds__(256) void k_attn(const short* __restrict__ qkv,
                                              const float* __restrict__ mask,
                                              const float* __restrict__ bias_table,
                                              short* __restrict__ Y) {
  __shared__ float mask_lds[64 * 64];   // [n][m ^ ((n&7)<<2)]
  __shared__ float bias_lds[4][128];
  __shared__ short p_lds[4][64][72];
  __shared__ short v_lds[4][64][40];

  const int t = threadIdx.x, wv = t >> 6, ln = t & 63;
  const int b = blockIdx.x;
  const int h = blockIdx.y * 4 + wv;
  const int hi = ln >> 4, lo = ln & 15;

  // stage mask (XOR-swizzled on 4-float granularity)
  const float4* mk = (const float4*)(mask + (size_t)(b & 63) * 4096);
#pragma unroll
  for (int u = 0; u < 4; ++u) {
    int idx = t + 256 * u;
    int row = idx >> 4, c4 = (idx & 15) * 4;
    *(float4*)&mask_lds[row * 64 + (c4 ^ ((row & 7) << 2))] = mk[idx];
  }
  for (int u = ln; u < 127; u += 64) bias_lds[wv][u] = bias_table[u * 16 + h];

  const short* qb = qkv + (size_t)b * 64 * 1536 + h * 32;
  const short* vg = qb + 1024;
  // stage V (64 rows x 32 cols) via b128: lane u-loop row = u*16 + (ln>>2)
#pragma unroll
  for (int u = 0; u < 4; ++u) {
    int row = u * 16 + (ln >> 2), c8 = (ln & 3) * 8;
    *(s16x8*)&v_lds[wv][row][c8] = *(const s16x8*)(vg + (size_t)row * 1536 + c8);
  }
  __syncthreads();

  // ---- swapped QK^T ----
  s16x8 qf[4], kf[4];
#pragma unroll
  for (int i = 0; i < 4; ++i) {
    qf[i] = *(const s16x8*)(qb + (size_t)(16 * i + lo) * 1536 + hi * 8);
    kf[i] = *(const s16x8*)(qb + (size_t)(16 * i + lo) * 1536 + 512 + hi * 8);
  }
  f32x4 s2[4][4] = {};
#pragma unroll
  for (int j = 0; j < 4; ++j)
#pragma unroll
    for (int i = 0; i < 4; ++i)
      s2[j][i] = __builtin_amdgcn_mfma_f32_16x16x32_bf16(kf[j], qf[i], s2[j][i], 0, 0, 0);

  // ---- softmax: per lane 4 rows (i), 16 vals each; 4-lane reduce ----
  const float scale = 0.17677669529663687f;
#pragma unroll
  for (int i = 0; i < 4; ++i) {
    const int n = 16 * i + lo;
    const int msw = (n & 7) << 2;
    float x[16];
    float vmax = -1e30f;
#pragma unroll
    for (int j = 0; j < 4; ++j)
#pragma unroll
      for (int r = 0; r < 4; ++r) {
        int m = 16 * j + 4 * hi + r;
        float xx = s2[j][i][r] * scale + bias_lds[wv][n - m + 63] +
                   mask_lds[n * 64 + (m ^ msw)];
        x[j * 4 + r] = xx;
        vmax = fmaxf(vmax, xx);
      }
    vmax = fmaxf(vmax, __shfl_xor(vmax, 16, 64));
    vmax = fmaxf(vmax, __shfl_xor(vmax, 32, 64));
    float sum = 0.f;
#pragma unroll
    for (int u = 0; u < 16; ++u) {
      x[u] = __expf(x[u] - vmax);
      sum += x[u];
    }
    sum += __shfl_xor(sum, 16, 64);
    sum += __shfl_xor(sum, 32, 64);
    float rsv = 1.0f / sum;
#pragma unroll
    for (int j = 0; j < 4; ++j)
#pragma unroll
      for (int rp = 0; rp < 2; ++rp)
        *(uint32_t*)&p_lds[wv][n][16 * j + 4 * hi + rp * 2] =
            pack2bf(x[j * 4 + rp * 2] * rsv, x[j * 4 + rp * 2 + 1] * rsv);
  }

  // ---- PV: O^T = mfma(V^T, P^T) ----
  f32x4 o2[2][4] = {};
#pragma unroll
  for (int kk = 0; kk < 2; ++kk) {
    s16x8 pa[4];
#pragma unroll
    for (int i2 = 0; i2 < 4; ++i2)
      pa[i2] = *(const s16x8*)&p_lds[wv][16 * i2 + lo][kk * 32 + hi * 8];
#pragma unroll
    for (int j2 = 0; j2 < 2; ++j2) {
      s16x8 vf;
#pragma unroll
      for (int jj = 0; jj < 8; ++jj)
        vf[jj] = v_lds[wv][kk * 32 + hi * 8 + jj][16 * j2 + lo];
#pragma unroll
      for (int i2 = 0; i2 < 4; ++i2)
        o2[j2][i2] = __builtin_amdgcn_mfma_f32_16x16x32_bf16(vf, pa[i2], o2[j2][i2], 0, 0, 0);
    }
  }

  // ---- packed Y stores: n = 16*i2+lo, d = 16*j2+4*hi+r (r consecutive) ----
  const int rr = h * 64 + (b >> 4);
#pragma unroll
  for (int i2 = 0; i2 < 4; ++i2) {
    int ss = (b & 15) * 4 + i2;
    short* yr = Y + ((size_t)rr * 64 + ss) * 512 + lo * 32 + 4 * hi;
#pragma unroll
    for (int j2 = 0; j2 < 2; ++j2) {
      uint2 pk;
      pk.x = pack2bf(o2[j2][i2][0], o2[j2][i2][1]);
      pk.y = pack2bf(o2[j2][i2][2], o2[j2][i2][3]);
      *(uint2*)(yr + 16 * j2) = pk;
    }
  }
}

extern "C" void kernel_launch(void* const* d_in, const int* in_sizes, int n_in,
                              void* d_out, int out_size, void* d_ws, size_t ws_size,
                              hipStream_t stream) {
  const float* x      = (const float*)d_in[0];
  const float* mask   = (const float*)d_in[1];
  const float* qkv_w  = (const float*)d_in[2];
  const float* qkv_b  = (const float*)d_in[3];
  const float* proj_w = (const float*)d_in[4];
  const float* proj_b = (const float*)d_in[5];
  const float* btab   = (const float*)d_in[6];
  float* out = (float*)d_out;

  char* w = (char*)d_ws;
  short* qkv_ws = (short*)w;                                             // 192 MiB
  short* xbf    = (short*)(w + (size_t)65536 * 1536 * 2);                // 64 MiB
  short* Y      = xbf;                                                   // reuse after GEMM1
  short* wT     = (short*)(w + (size_t)65536 * 1536 * 2 + (size_t)65536 * 512 * 2);
  short* projT  = wT + 1536 * 512;

  k_cast_bf16<<<16384, 256, 0, stream>>>(x, xbf, 33554432 / 8);
  k_transpose_cast<<<dim3(24, 8), 256, 0, stream>>>(qkv_w, wT, 512, 1536);
  k_transpose_cast<<<dim3(8, 8), 256, 0, stream>>>(proj_w, projT, 512, 512);
  k_gemm256p<false, 6, 512><<<256, 512, 0, stream>>>(xbf, wT, qkv_b, qkv_ws, 1536, 6);
  k_attn<<<dim3(1024, 4), 256, 0, stream>>>(qkv_ws, mask, btab, Y);
  k_gemm256p<true, 2, 512><<<256, 512, 0, stream>>>(Y, projT, proj_b, out, 512, 2);
}